// Round 4
// baseline (120.389 us; speedup 1.0000x reference)
//
#include <hip/hip_runtime.h>
#include <math.h>

#define SDIM 376
#define ADIM 17
#define DIN  393
#define H1   400
#define H2   300
#define TSTEPS 32
#define KP 416   // 13*32
#define NCMAX 50 // colmax partial blocks (8 rows each)

typedef __bf16 bf16x8 __attribute__((ext_vector_type(8)));
typedef float  f32x4  __attribute__((ext_vector_type(4)));

// ---------- K0 (fused prep): pack input->bf16 | W1 transpose->bf16 | W2 colmax partials ----------
__global__ __launch_bounds__(256) void prep_fused(
    const float* __restrict__ state, const float* __restrict__ action,
    const float* __restrict__ W1, const float* __restrict__ W2,
    __bf16* __restrict__ inpb, __bf16* __restrict__ W1T,
    float* __restrict__ partial, int B, int npack, int nw1t) {
    const int bid = blockIdx.x, tid = threadIdx.x;
    if (bid < npack) {
        // pack concat(state,action,0) -> bf16 [B][416], 8 cols/thread
        int idx = bid * 256 + tid;
        int r = idx / 52, c = idx - r * 52;
        if (r >= B) return;
        int g0 = c * 8;
        float v[8];
        if (g0 + 7 < SDIM) {
            float4 a = *(const float4*)&state[r * SDIM + g0];
            float4 b = *(const float4*)&state[r * SDIM + g0 + 4];
            v[0]=a.x; v[1]=a.y; v[2]=a.z; v[3]=a.w; v[4]=b.x; v[5]=b.y; v[6]=b.z; v[7]=b.w;
        } else {
            #pragma unroll
            for (int e = 0; e < 8; ++e) {
                int k = g0 + e;
                v[e] = (k < SDIM) ? state[r * SDIM + k]
                     : (k < DIN)  ? action[r * ADIM + k - SDIM] : 0.f;
            }
        }
        bf16x8 o;
        #pragma unroll
        for (int e = 0; e < 8; ++e) o[e] = (__bf16)v[e];
        *(bf16x8*)&inpb[r * KP + g0] = o;
    } else if (bid < npack + nw1t) {
        // W1 [393][400] f32 -> W1T [400][416] bf16
        int idx = (bid - npack) * 256 + tid;
        if (idx >= H1 * KP) return;
        int n = idx / KP, k = idx - n * KP;
        W1T[idx] = (__bf16)((k < DIN) ? W1[k * H1 + n] : 0.f);
    } else {
        // W2 colmax partial: block cb owns rows cb*8..cb*8+7; threads own cols (coalesced)
        int cb = bid - npack - nw1t;   // 0..49
        int r0 = cb * 8;
        for (int j = tid; j < H2; j += 256) {
            float m = 0.f;  // implicitly max(w,0): start at 0
            #pragma unroll
            for (int i = 0; i < 8; ++i) m = fmaxf(m, W2[(r0 + i) * H2 + j]);
            partial[cb * H2 + j] = m;
        }
    }
}

// ---------- K1: finalize stats: thresh = min_j (0.998-b2[j])/colmax_j; g = closed-form out ----------
__global__ void finalize_stats(const float* __restrict__ partial,
                               const float* __restrict__ b2,
                               const float* __restrict__ b3,
                               float* __restrict__ stats) {
    __shared__ float red[512];
    int j = threadIdx.x;  // 320 threads
    float thr_j = 3.0e38f;
    if (j < H2) {
        float cm = 0.f;
        #pragma unroll 10
        for (int p = 0; p < NCMAX; ++p) cm = fmaxf(cm, partial[p * H2 + j]);
        float num = 0.998f - b2[j];
        thr_j = (cm > 1e-20f) ? num / cm : (num >= 0.f ? 3.0e38f : -1.0f);
    }
    red[j] = thr_j;
    if (j < 192) red[320 + j] = 3.0e38f;
    __syncthreads();
    #pragma unroll
    for (int off = 256; off >= 1; off >>= 1) {
        if (j < off) red[j] = fminf(red[j], red[j + off]);
        __syncthreads();
    }
    if (j == 0) stats[0] = red[0];
    if (j < ADIM) {
        float b = b3[j], v3 = 0.f, vm = -3.0e38f;
        for (int t = 0; t < TSTEPS; ++t) { v3 += (b - v3) * 0.5f; vm = fmaxf(vm, v3); }
        stats[1 + j] = 0.05f * tanhf(vm);
    }
}

// ---------- K2: GEMM -> spike mask. NO LDS, NO barriers: frags are direct 16B global loads.
// A-frag: inpb[(row)*KP + k0 + quad*8] ; B-frag: W1T[(col)*KP + k0 + quad*8] (both contiguous).
// inpb/W1T are L2-resident; K-loop fully unrolled -> pure load->MFMA stream. ----------
__global__ __launch_bounds__(256) void gemm_mask(
    const __bf16* __restrict__ inpb, const __bf16* __restrict__ W1T,
    const float* __restrict__ b1, unsigned short* __restrict__ maskbuf) {
    const int tid = threadIdx.x, wave = tid >> 6, lane = tid & 63;
    const int quad = lane >> 4, l16 = lane & 15;
    const int bm0 = blockIdx.x * 64 + wave * 16;   // this wave's 16 rows
    const int bn0 = blockIdx.y * 80;

    f32x4 acc[5];
    #pragma unroll
    for (int n = 0; n < 5; ++n) acc[n] = (f32x4){0.f, 0.f, 0.f, 0.f};

    const __bf16* ap = inpb + (size_t)(bm0 + l16) * KP + quad * 8;
    const __bf16* bp = W1T + (size_t)(bn0 + l16) * KP + quad * 8;

    #pragma unroll
    for (int k0 = 0; k0 < KP; k0 += 32) {
        bf16x8 af = *(const bf16x8*)(ap + k0);
        #pragma unroll
        for (int n = 0; n < 5; ++n) {
            bf16x8 bfrag = *(const bf16x8*)(bp + n * 16 * KP + k0);
            acc[n] = __builtin_amdgcn_mfma_f32_16x16x32_bf16(af, bfrag, acc[n], 0, 0, 0);
        }
    }

    float b1v[5];
    #pragma unroll
    for (int n = 0; n < 5; ++n) b1v[n] = b1[bn0 + n * 16 + l16];
    const int cbase = bn0 >> 4;  // chunk base = blockIdx.y*5
    #pragma unroll
    for (int n = 0; n < 5; ++n)
        #pragma unroll
        for (int reg = 0; reg < 4; ++reg) {
            // 0.99: superset of {x1_ref >= 1}; bf16 GEMM |err| << 0.01 at this K/scale
            unsigned long long bal = __ballot(acc[n][reg] + b1v[n] >= 0.99f);
            if (l16 == 0)
                maskbuf[(size_t)(bm0 + quad * 4 + reg) * 32 + cbase + n] =
                    (unsigned short)(bal >> (quad * 16));
        }
}

// ---------- K3: tiered SNN. One wave/row; tier1 closed-form, tier2 gather-bound, tier3 sim ----------
__global__ __launch_bounds__(256) void snn_actor(
    const unsigned long long* __restrict__ mask64,  // [B][8]
    const float* __restrict__ stats,
    const float* __restrict__ state, const float* __restrict__ action,
    const float* __restrict__ W1, const float* __restrict__ b1,
    const float* __restrict__ W2, const float* __restrict__ b2,
    const float* __restrict__ W3, const float* __restrict__ b3,
    float* __restrict__ out) {
    const int lane = threadIdx.x & 63;
    const int row  = blockIdx.x * 4 + (threadIdx.x >> 6);

    unsigned long long mw = 0;
    if (lane < 7) {
        mw = mask64[row * 8 + lane];
        if (lane == 6) mw &= 0xFFFFULL;  // chunks 25..27 are unwritten ws
    }
    int pc = __popcll(mw);
    pc += __shfl_down(pc, 4);
    pc += __shfl_down(pc, 2);
    pc += __shfl_down(pc, 1);
    const int cnt = __shfl(pc, 0);

    const float act = (lane < ADIM) ? action[row * ADIM + lane] : 0.f;
    const float gv  = (lane < ADIM) ? stats[1 + lane] : 0.f;

    // tier1: cnt * colmax bound (proves v2<1 forever -> s2==0 -> closed form)
    bool closed = ((float)cnt <= stats[0]);
    if (!closed) {
        // tier2: exact bound b2[j] + sum_{i in set} max(W2[i][j],0) < 0.999
        float bound[5];
        #pragma unroll
        for (int c = 0; c < 5; ++c) { int j = lane + 64 * c; bound[c] = (j < H2) ? b2[j] : 0.f; }
        for (int w = 0; w < 7; ++w) {
            unsigned long long m = __shfl(mw, w);
            while (m) {
                int b = __builtin_ctzll(m); m &= m - 1;
                const float* wr = W2 + (w * 64 + b) * H2;
                #pragma unroll
                for (int c = 0; c < 5; ++c) {
                    int j = lane + 64 * c;
                    if (j < H2) bound[c] += fmaxf(wr[j], 0.f);
                }
            }
        }
        bool ok = true;
        #pragma unroll
        for (int c = 0; c < 5; ++c) ok = ok && (bound[c] < 0.999f);
        closed = __all(ok);
    }
    if (closed) {
        if (lane < ADIM) out[row * ADIM + lane] = fminf(fmaxf(gv + act, -1.f), 1.f);
        return;  // wave-uniform
    }

    // tier3 (soundness net, never taken in practice): recompute x1 in f32, full sim
    float x1v[7];
    #pragma unroll
    for (int s = 0; s < 7; ++s) { int col = lane + 64 * s; x1v[s] = (col < H1) ? b1[col] : 0.f; }
    for (int k = 0; k < DIN; ++k) {
        float ik = (k < SDIM) ? state[row * SDIM + k] : action[row * ADIM + k - SDIM];
        #pragma unroll
        for (int s = 0; s < 7; ++s) {
            int col = lane + 64 * s;
            if (col < H1) x1v[s] += ik * W1[k * H1 + col];
        }
    }
    float b2v[5];
    #pragma unroll
    for (int c = 0; c < 5; ++c) { int j = lane + 64 * c; b2v[c] = (j < H2) ? b2[j] : 0.f; }
    const float b3v = (lane < ADIM) ? b3[lane] : 0.f;
    float v1[7], v2[5], v3 = 0.f, vmax = -3.0e38f;
    #pragma unroll
    for (int s = 0; s < 7; ++s) v1[s] = 0.f;
    #pragma unroll
    for (int c = 0; c < 5; ++c) v2[c] = 0.f;
    for (int t = 0; t < TSTEPS; ++t) {
        float x2[5];
        #pragma unroll
        for (int c = 0; c < 5; ++c) x2[c] = b2v[c];
        #pragma unroll
        for (int s = 0; s < 7; ++s) {
            float v = v1[s] + (x1v[s] - v1[s]) * 0.5f;
            bool sp = v >= 1.0f;
            v1[s] = sp ? 0.f : v;
            unsigned long long m = __ballot(sp);
            while (m) {
                int j = __builtin_ctzll(m); m &= m - 1;
                const float* wr = W2 + (s * 64 + j) * H2;
                #pragma unroll
                for (int c = 0; c < 5; ++c) {
                    int col = lane + 64 * c;
                    if (col < H2) x2[c] += wr[col];
                }
            }
        }
        float x3 = b3v;
        #pragma unroll
        for (int c = 0; c < 5; ++c) {
            float v = v2[c] + (x2[c] - v2[c]) * 0.5f;
            int col = lane + 64 * c;
            bool sp = (col < H2) && (v >= 1.0f);
            v2[c] = sp ? 0.f : v;
            unsigned long long m = __ballot(sp);
            while (m) {
                int j = __builtin_ctzll(m); m &= m - 1;
                if (lane < ADIM) x3 += W3[(c * 64 + j) * ADIM + lane];
            }
        }
        v3 += (x3 - v3) * 0.5f;
        vmax = fmaxf(vmax, v3);
    }
    if (lane < ADIM)
        out[row * ADIM + lane] = fminf(fmaxf(0.05f * tanhf(vmax) + act, -1.f), 1.f);
}

extern "C" void kernel_launch(void* const* d_in, const int* in_sizes, int n_in,
                              void* d_out, int out_size, void* d_ws, size_t ws_size,
                              hipStream_t stream) {
    const float* state  = (const float*)d_in[0];
    const float* action = (const float*)d_in[1];
    const float* W1     = (const float*)d_in[2];
    const float* b1     = (const float*)d_in[3];
    const float* W2     = (const float*)d_in[4];
    const float* b2     = (const float*)d_in[5];
    const float* W3     = (const float*)d_in[6];
    const float* b3     = (const float*)d_in[7];
    float* out = (float*)d_out;

    const int B = in_sizes[0] / SDIM;  // 8192

    char* p = (char*)d_ws;
    __bf16* inpb = (__bf16*)p;                 p += (size_t)B * KP * 2;
    __bf16* W1T  = (__bf16*)p;                 p += (size_t)H1 * KP * 2;
    unsigned short* maskbuf = (unsigned short*)p;
    unsigned long long* mask64 = (unsigned long long*)p;  p += (size_t)B * 32 * 2;
    float* partial = (float*)p;                p += (size_t)NCMAX * H2 * 4;
    float* stats = (float*)p;

    const int npack = (B * 52 + 255) / 256;        // 1664
    const int nw1t  = (H1 * KP + 255) / 256;       // 650
    prep_fused<<<npack + nw1t + NCMAX, 256, 0, stream>>>(
        state, action, W1, W2, inpb, W1T, partial, B, npack, nw1t);
    finalize_stats<<<1, 320, 0, stream>>>(partial, b2, b3, stats);
    gemm_mask<<<dim3(B / 64, 5), 256, 0, stream>>>(inpb, W1T, b1, maskbuf);
    snn_actor<<<B / 4, 256, 0, stream>>>(mask64, stats, state, action,
                                         W1, b1, W2, b2, W3, b3, out);
}

// Round 5
// 109.548 us; speedup vs baseline: 1.0990x; 1.0990x over previous
//
#include <hip/hip_runtime.h>
#include <math.h>

#define SDIM 376
#define ADIM 17
#define DIN  393
#define H1   400
#define H2   300
#define TSTEPS 32
#define KP 416   // 13*32

typedef __bf16 bf16x8 __attribute__((ext_vector_type(8)));
typedef float  f32x4  __attribute__((ext_vector_type(4)));

// ---------- K0 (fused prep): pack input->bf16 [B][416] | W1 transpose->bf16 [400][416] ----------
__global__ __launch_bounds__(256) void prep_fused(
    const float* __restrict__ state, const float* __restrict__ action,
    const float* __restrict__ W1,
    __bf16* __restrict__ inpb, __bf16* __restrict__ W1T,
    int B, int npack) {
    const int bid = blockIdx.x, tid = threadIdx.x;
    if (bid < npack) {
        // pack concat(state,action,0) -> bf16, 8 cols/thread, coalesced
        int idx = bid * 256 + tid;
        int r = idx / 52, c = idx - r * 52;
        if (r >= B) return;
        int g0 = c * 8;
        float v[8];
        if (g0 + 7 < SDIM) {
            float4 a = *(const float4*)&state[r * SDIM + g0];
            float4 b = *(const float4*)&state[r * SDIM + g0 + 4];
            v[0]=a.x; v[1]=a.y; v[2]=a.z; v[3]=a.w; v[4]=b.x; v[5]=b.y; v[6]=b.z; v[7]=b.w;
        } else {
            #pragma unroll
            for (int e = 0; e < 8; ++e) {
                int k = g0 + e;
                v[e] = (k < SDIM) ? state[r * SDIM + k]
                     : (k < DIN)  ? action[r * ADIM + k - SDIM] : 0.f;
            }
        }
        bf16x8 o;
        #pragma unroll
        for (int e = 0; e < 8; ++e) o[e] = (__bf16)v[e];
        *(bf16x8*)&inpb[r * KP + g0] = o;
    } else {
        // W1 [393][400] f32 -> W1T [400][416] bf16 (scattered reads hit L2; writes coalesced)
        int idx = (bid - npack) * 256 + tid;
        if (idx >= H1 * KP) return;
        int n = idx / KP, k = idx - n * KP;
        W1T[idx] = (__bf16)((k < DIN) ? W1[k * H1 + n] : 0.f);
    }
}

// ---------- K1: GEMM -> spike mask. NO LDS, NO barriers: frags are direct 16B global loads.
// A-frag: inpb[row*KP + k0 + quad*8] ; B-frag: W1T[col*KP + k0 + quad*8] (both contiguous).
// W1T (332 KB) L2-resident; K-loop fully unrolled -> pure load->MFMA stream. ----------
__global__ __launch_bounds__(256) void gemm_mask(
    const __bf16* __restrict__ inpb, const __bf16* __restrict__ W1T,
    const float* __restrict__ b1, unsigned short* __restrict__ maskbuf) {
    const int tid = threadIdx.x, wave = tid >> 6, lane = tid & 63;
    const int quad = lane >> 4, l16 = lane & 15;
    const int bm0 = blockIdx.x * 64 + wave * 16;   // this wave's 16 rows
    const int bn0 = blockIdx.y * 80;

    f32x4 acc[5];
    #pragma unroll
    for (int n = 0; n < 5; ++n) acc[n] = (f32x4){0.f, 0.f, 0.f, 0.f};

    const __bf16* ap = inpb + (size_t)(bm0 + l16) * KP + quad * 8;
    const __bf16* bp = W1T + (size_t)(bn0 + l16) * KP + quad * 8;

    #pragma unroll
    for (int k0 = 0; k0 < KP; k0 += 32) {
        bf16x8 af = *(const bf16x8*)(ap + k0);
        #pragma unroll
        for (int n = 0; n < 5; ++n) {
            bf16x8 bfrag = *(const bf16x8*)(bp + n * 16 * KP + k0);
            acc[n] = __builtin_amdgcn_mfma_f32_16x16x32_bf16(af, bfrag, acc[n], 0, 0, 0);
        }
    }

    float b1v[5];
    #pragma unroll
    for (int n = 0; n < 5; ++n) b1v[n] = b1[bn0 + n * 16 + l16];
    const int cbase = bn0 >> 4;  // chunk base = blockIdx.y*5
    #pragma unroll
    for (int n = 0; n < 5; ++n)
        #pragma unroll
        for (int reg = 0; reg < 4; ++reg) {
            // 0.99: superset of {x1_ref >= 1}; bf16 GEMM |err| << 0.01 at this K/scale
            unsigned long long bal = __ballot(acc[n][reg] + b1v[n] >= 0.99f);
            if (l16 == 0)
                maskbuf[(size_t)(bm0 + quad * 4 + reg) * 32 + cbase + n] =
                    (unsigned short)(bal >> (quad * 16));
        }
}

// ---------- K2: SNN. One wave/row. Exact no-spike bound for every row (no stats dep);
// closed-form g computed in-register; tier-3 full sim only as soundness net. ----------
__global__ __launch_bounds__(256) void snn_actor(
    const unsigned long long* __restrict__ mask64,  // [B][8]
    const float* __restrict__ state, const float* __restrict__ action,
    const float* __restrict__ W1, const float* __restrict__ b1,
    const float* __restrict__ W2, const float* __restrict__ b2,
    const float* __restrict__ W3, const float* __restrict__ b3,
    float* __restrict__ out) {
    const int lane = threadIdx.x & 63;
    const int row  = blockIdx.x * 4 + (threadIdx.x >> 6);

    unsigned long long mw = 0;
    if (lane < 7) {
        mw = mask64[row * 8 + lane];
        if (lane == 6) mw &= 0xFFFFULL;  // chunks 25..27 are unwritten ws
    }

    const float act = (lane < ADIM) ? action[row * ADIM + lane] : 0.f;
    const float b3v = (lane < ADIM) ? b3[lane] : 0.f;

    // closed-form output if s2==0: v3 charges toward b3; g = 0.05*tanh(max_t v3_t)
    float gv;
    {
        float v3 = 0.f, vm = -3.0e38f;
        #pragma unroll
        for (int t = 0; t < TSTEPS; ++t) { v3 += (b3v - v3) * 0.5f; vm = fmaxf(vm, v3); }
        gv = 0.05f * tanhf(vm);
    }

    // exact bound: b2[j] + sum_{i in mask} max(W2[i][j],0) < 0.999 for all j
    // (mask superset of ever-spiking layer-1 neurons => by induction v2<1 forever => s2==0)
    float bound[5];
    #pragma unroll
    for (int c = 0; c < 5; ++c) { int j = lane + 64 * c; bound[c] = (j < H2) ? b2[j] : 0.f; }
    #pragma unroll 1
    for (int w = 0; w < 7; ++w) {
        unsigned long long m = __shfl(mw, w);
        while (m) {
            int b = __builtin_ctzll(m); m &= m - 1;
            const float* wr = W2 + (w * 64 + b) * H2;
            #pragma unroll
            for (int c = 0; c < 5; ++c) {
                int j = lane + 64 * c;
                if (j < H2) bound[c] += fmaxf(wr[j], 0.f);
            }
        }
    }
    bool ok = true;
    #pragma unroll
    for (int c = 0; c < 5; ++c) ok = ok && (bound[c] < 0.999f);
    if (__all(ok)) {
        if (lane < ADIM) out[row * ADIM + lane] = fminf(fmaxf(gv + act, -1.f), 1.f);
        return;  // wave-uniform
    }

    // tier3 (soundness net, never taken in practice): recompute x1 in f32, full sim
    float x1v[7];
    #pragma unroll
    for (int s = 0; s < 7; ++s) { int col = lane + 64 * s; x1v[s] = (col < H1) ? b1[col] : 0.f; }
    for (int k = 0; k < DIN; ++k) {
        float ik = (k < SDIM) ? state[row * SDIM + k] : action[row * ADIM + k - SDIM];
        #pragma unroll
        for (int s = 0; s < 7; ++s) {
            int col = lane + 64 * s;
            if (col < H1) x1v[s] += ik * W1[k * H1 + col];
        }
    }
    float b2v[5];
    #pragma unroll
    for (int c = 0; c < 5; ++c) { int j = lane + 64 * c; b2v[c] = (j < H2) ? b2[j] : 0.f; }
    float v1[7], v2[5], v3 = 0.f, vmax = -3.0e38f;
    #pragma unroll
    for (int s = 0; s < 7; ++s) v1[s] = 0.f;
    #pragma unroll
    for (int c = 0; c < 5; ++c) v2[c] = 0.f;
    for (int t = 0; t < TSTEPS; ++t) {
        float x2[5];
        #pragma unroll
        for (int c = 0; c < 5; ++c) x2[c] = b2v[c];
        #pragma unroll
        for (int s = 0; s < 7; ++s) {
            float v = v1[s] + (x1v[s] - v1[s]) * 0.5f;
            bool sp = v >= 1.0f;
            v1[s] = sp ? 0.f : v;
            unsigned long long m = __ballot(sp);
            while (m) {
                int j = __builtin_ctzll(m); m &= m - 1;
                const float* wr = W2 + (s * 64 + j) * H2;
                #pragma unroll
                for (int c = 0; c < 5; ++c) {
                    int col = lane + 64 * c;
                    if (col < H2) x2[c] += wr[col];
                }
            }
        }
        float x3 = b3v;
        #pragma unroll
        for (int c = 0; c < 5; ++c) {
            float v = v2[c] + (x2[c] - v2[c]) * 0.5f;
            int col = lane + 64 * c;
            bool sp = (col < H2) && (v >= 1.0f);
            v2[c] = sp ? 0.f : v;
            unsigned long long m = __ballot(sp);
            while (m) {
                int j = __builtin_ctzll(m); m &= m - 1;
                if (lane < ADIM) x3 += W3[(c * 64 + j) * ADIM + lane];
            }
        }
        v3 += (x3 - v3) * 0.5f;
        vmax = fmaxf(vmax, v3);
    }
    if (lane < ADIM)
        out[row * ADIM + lane] = fminf(fmaxf(0.05f * tanhf(vmax) + act, -1.f), 1.f);
}

extern "C" void kernel_launch(void* const* d_in, const int* in_sizes, int n_in,
                              void* d_out, int out_size, void* d_ws, size_t ws_size,
                              hipStream_t stream) {
    const float* state  = (const float*)d_in[0];
    const float* action = (const float*)d_in[1];
    const float* W1     = (const float*)d_in[2];
    const float* b1     = (const float*)d_in[3];
    const float* W2     = (const float*)d_in[4];
    const float* b2     = (const float*)d_in[5];
    const float* W3     = (const float*)d_in[6];
    const float* b3     = (const float*)d_in[7];
    float* out = (float*)d_out;

    const int B = in_sizes[0] / SDIM;  // 8192

    char* p = (char*)d_ws;
    __bf16* inpb = (__bf16*)p;                 p += (size_t)B * KP * 2;
    __bf16* W1T  = (__bf16*)p;                 p += (size_t)H1 * KP * 2;
    unsigned short* maskbuf = (unsigned short*)p;
    unsigned long long* mask64 = (unsigned long long*)p;

    const int npack = (B * 52 + 255) / 256;        // 1664
    const int nw1t  = (H1 * KP + 255) / 256;       // 650
    prep_fused<<<npack + nw1t, 256, 0, stream>>>(state, action, W1, inpb, W1T, B, npack);
    gemm_mask<<<dim3(B / 64, 5), 256, 0, stream>>>(inpb, W1T, b1, maskbuf);
    snn_actor<<<B / 4, 256, 0, stream>>>(mask64, state, action,
                                         W1, b1, W2, b2, W3, b3, out);
}

// Round 6
// 103.698 us; speedup vs baseline: 1.1610x; 1.0564x over previous
//
#include <hip/hip_runtime.h>
#include <math.h>

#define SDIM 376
#define ADIM 17
#define DIN  393
#define H1   400
#define H2   300
#define TSTEPS 32
#define KP 416   // 13*32
#define NKT 13   // K tiles of 32

typedef __bf16 bf16x8 __attribute__((ext_vector_type(8)));
typedef float  f32x4  __attribute__((ext_vector_type(4)));

// Fragment-major layouts: frag for (tile, kt) is 64 lanes x 8 bf16, contiguous:
//   A_sw[((mtile*13 + kt)*64 + lane)*8 + e]   lane = quad*16 + (row&15), e = k&7, quad=(k>>3)&3
//   B_sw[((ntile*13 + kt)*64 + lane)*8 + e]   lane = quad*16 + (col&15)
// => every MFMA fragment load is ONE coalesced 1KB wave transaction (vs 832B-stride gather).

// ---------- K0 (fused prep): pack input -> A_sw | W1 -> B_sw ----------
__global__ __launch_bounds__(256) void prep_fused(
    const float* __restrict__ state, const float* __restrict__ action,
    const float* __restrict__ W1,
    __bf16* __restrict__ A_sw, __bf16* __restrict__ B_sw,
    int B, int npack) {
    const int bid = blockIdx.x, tid = threadIdx.x;
    if (bid < npack) {
        // pack concat(state,action,0): thread -> (row r, 8-col chunk c); source reads coalesced
        int idx = bid * 256 + tid;
        int r = idx / 52, c = idx - r * 52;
        if (r >= B) return;
        int g0 = c * 8;
        float v[8];
        if (g0 + 7 < SDIM) {
            float4 a = *(const float4*)&state[r * SDIM + g0];
            float4 b = *(const float4*)&state[r * SDIM + g0 + 4];
            v[0]=a.x; v[1]=a.y; v[2]=a.z; v[3]=a.w; v[4]=b.x; v[5]=b.y; v[6]=b.z; v[7]=b.w;
        } else {
            #pragma unroll
            for (int e = 0; e < 8; ++e) {
                int k = g0 + e;
                v[e] = (k < SDIM) ? state[r * SDIM + k]
                     : (k < DIN)  ? action[r * ADIM + k - SDIM] : 0.f;
            }
        }
        bf16x8 o;
        #pragma unroll
        for (int e = 0; e < 8; ++e) o[e] = (__bf16)v[e];
        int kt = g0 >> 5, quad = (g0 >> 3) & 3;
        *(bf16x8*)&A_sw[(((size_t)(r >> 4) * NKT + kt) * 64 + (quad << 4) + (r & 15)) * 8] = o;
    } else {
        // W1 [k][n] -> B_sw, k-major thread mapping => W1 reads fully coalesced
        int idx = (bid - npack) * 256 + tid;
        if (idx >= H1 * KP) return;
        int k = idx / H1, n = idx - k * H1;
        float val = (k < DIN) ? W1[k * H1 + n] : 0.f;
        int ntile = n >> 4, kt = k >> 5, quad = (k >> 3) & 3;
        B_sw[(((size_t)ntile * NKT + kt) * 64 + (quad << 4) + (n & 15)) * 8 + (k & 7)] = (__bf16)val;
    }
}

// ---------- K1: GEMM -> spike mask. No LDS, no barriers; all loads coalesced 1KB/wave ----------
__global__ __launch_bounds__(256) void gemm_mask(
    const __bf16* __restrict__ A_sw, const __bf16* __restrict__ B_sw,
    const float* __restrict__ b1, unsigned short* __restrict__ maskbuf) {
    const int tid = threadIdx.x, wave = tid >> 6, lane = tid & 63;
    const int quad = lane >> 4, l16 = lane & 15;
    const int mtile = blockIdx.x * 4 + wave;       // this wave's 16 rows
    const int bn0 = blockIdx.y * 80;               // 5 n-tiles

    f32x4 acc[5];
    #pragma unroll
    for (int n = 0; n < 5; ++n) acc[n] = (f32x4){0.f, 0.f, 0.f, 0.f};

    const __bf16* ap = A_sw + ((size_t)mtile * NKT * 64 + lane) * 8;
    const __bf16* bp = B_sw + ((size_t)(blockIdx.y * 5) * NKT * 64 + lane) * 8;

    #pragma unroll
    for (int kt = 0; kt < NKT; ++kt) {
        bf16x8 af = *(const bf16x8*)(ap + (size_t)kt * 512);
        #pragma unroll
        for (int n = 0; n < 5; ++n) {
            bf16x8 bfrag = *(const bf16x8*)(bp + ((size_t)n * NKT + kt) * 512);
            acc[n] = __builtin_amdgcn_mfma_f32_16x16x32_bf16(af, bfrag, acc[n], 0, 0, 0);
        }
    }

    float b1v[5];
    #pragma unroll
    for (int n = 0; n < 5; ++n) b1v[n] = b1[bn0 + n * 16 + l16];
    const int cbase = bn0 >> 4;  // chunk base = blockIdx.y*5
    const int bm0 = mtile * 16;
    #pragma unroll
    for (int n = 0; n < 5; ++n)
        #pragma unroll
        for (int reg = 0; reg < 4; ++reg) {
            // 0.99: superset of {x1_ref >= 1}; bf16 GEMM |err| << 0.01 at this K/scale
            unsigned long long bal = __ballot(acc[n][reg] + b1v[n] >= 0.99f);
            if (l16 == 0)
                maskbuf[(size_t)(bm0 + quad * 4 + reg) * 32 + cbase + n] =
                    (unsigned short)(bal >> (quad * 16));
        }
}

// ---------- K2: SNN. One wave/row. Exact no-spike bound per row; closed-form out;
// tier-3 full sim only as soundness net. ----------
__global__ __launch_bounds__(256) void snn_actor(
    const unsigned long long* __restrict__ mask64,  // [B][8]
    const float* __restrict__ state, const float* __restrict__ action,
    const float* __restrict__ W1, const float* __restrict__ b1,
    const float* __restrict__ W2, const float* __restrict__ b2,
    const float* __restrict__ W3, const float* __restrict__ b3,
    float* __restrict__ out) {
    const int lane = threadIdx.x & 63;
    const int row  = blockIdx.x * 4 + (threadIdx.x >> 6);

    unsigned long long mw = 0;
    if (lane < 7) {
        mw = mask64[row * 8 + lane];
        if (lane == 6) mw &= 0xFFFFULL;  // chunks 25..27 are unwritten ws
    }

    const float act = (lane < ADIM) ? action[row * ADIM + lane] : 0.f;
    const float b3v = (lane < ADIM) ? b3[lane] : 0.f;

    // closed-form output if s2==0: v3 charges toward b3; g = 0.05*tanh(max_t v3_t)
    float gv;
    {
        float v3 = 0.f, vm = -3.0e38f;
        #pragma unroll
        for (int t = 0; t < TSTEPS; ++t) { v3 += (b3v - v3) * 0.5f; vm = fmaxf(vm, v3); }
        gv = 0.05f * tanhf(vm);
    }

    // exact bound: b2[j] + sum_{i in mask} max(W2[i][j],0) < 0.999 for all j
    // (mask superset of ever-spiking layer-1 neurons => by induction v2<1 forever => s2==0)
    float bound[5];
    #pragma unroll
    for (int c = 0; c < 5; ++c) { int j = lane + 64 * c; bound[c] = (j < H2) ? b2[j] : 0.f; }
    #pragma unroll 1
    for (int w = 0; w < 7; ++w) {
        unsigned long long m = __shfl(mw, w);
        while (m) {
            int b = __builtin_ctzll(m); m &= m - 1;
            const float* wr = W2 + (w * 64 + b) * H2;
            #pragma unroll
            for (int c = 0; c < 5; ++c) {
                int j = lane + 64 * c;
                if (j < H2) bound[c] += fmaxf(wr[j], 0.f);
            }
        }
    }
    bool ok = true;
    #pragma unroll
    for (int c = 0; c < 5; ++c) ok = ok && (bound[c] < 0.999f);
    if (__all(ok)) {
        if (lane < ADIM) out[row * ADIM + lane] = fminf(fmaxf(gv + act, -1.f), 1.f);
        return;  // wave-uniform
    }

    // tier3 (soundness net, never taken in practice): recompute x1 in f32, full sim
    float x1v[7];
    #pragma unroll
    for (int s = 0; s < 7; ++s) { int col = lane + 64 * s; x1v[s] = (col < H1) ? b1[col] : 0.f; }
    for (int k = 0; k < DIN; ++k) {
        float ik = (k < SDIM) ? state[row * SDIM + k] : action[row * ADIM + k - SDIM];
        #pragma unroll
        for (int s = 0; s < 7; ++s) {
            int col = lane + 64 * s;
            if (col < H1) x1v[s] += ik * W1[k * H1 + col];
        }
    }
    float b2v[5];
    #pragma unroll
    for (int c = 0; c < 5; ++c) { int j = lane + 64 * c; b2v[c] = (j < H2) ? b2[j] : 0.f; }
    float v1[7], v2[5], v3 = 0.f, vmax = -3.0e38f;
    #pragma unroll
    for (int s = 0; s < 7; ++s) v1[s] = 0.f;
    #pragma unroll
    for (int c = 0; c < 5; ++c) v2[c] = 0.f;
    for (int t = 0; t < TSTEPS; ++t) {
        float x2[5];
        #pragma unroll
        for (int c = 0; c < 5; ++c) x2[c] = b2v[c];
        #pragma unroll
        for (int s = 0; s < 7; ++s) {
            float v = v1[s] + (x1v[s] - v1[s]) * 0.5f;
            bool sp = v >= 1.0f;
            v1[s] = sp ? 0.f : v;
            unsigned long long m = __ballot(sp);
            while (m) {
                int j = __builtin_ctzll(m); m &= m - 1;
                const float* wr = W2 + (s * 64 + j) * H2;
                #pragma unroll
                for (int c = 0; c < 5; ++c) {
                    int col = lane + 64 * c;
                    if (col < H2) x2[c] += wr[col];
                }
            }
        }
        float x3 = b3v;
        #pragma unroll
        for (int c = 0; c < 5; ++c) {
            float v = v2[c] + (x2[c] - v2[c]) * 0.5f;
            int col = lane + 64 * c;
            bool sp = (col < H2) && (v >= 1.0f);
            v2[c] = sp ? 0.f : v;
            unsigned long long m = __ballot(sp);
            while (m) {
                int j = __builtin_ctzll(m); m &= m - 1;
                if (lane < ADIM) x3 += W3[(c * 64 + j) * ADIM + lane];
            }
        }
        v3 += (x3 - v3) * 0.5f;
        vmax = fmaxf(vmax, v3);
    }
    if (lane < ADIM)
        out[row * ADIM + lane] = fminf(fmaxf(0.05f * tanhf(vmax) + act, -1.f), 1.f);
}

extern "C" void kernel_launch(void* const* d_in, const int* in_sizes, int n_in,
                              void* d_out, int out_size, void* d_ws, size_t ws_size,
                              hipStream_t stream) {
    const float* state  = (const float*)d_in[0];
    const float* action = (const float*)d_in[1];
    const float* W1     = (const float*)d_in[2];
    const float* b1     = (const float*)d_in[3];
    const float* W2     = (const float*)d_in[4];
    const float* b2     = (const float*)d_in[5];
    const float* W3     = (const float*)d_in[6];
    const float* b3     = (const float*)d_in[7];
    float* out = (float*)d_out;

    const int B = in_sizes[0] / SDIM;  // 8192

    char* p = (char*)d_ws;
    __bf16* A_sw = (__bf16*)p;                 p += (size_t)B * KP * 2;
    __bf16* B_sw = (__bf16*)p;                 p += (size_t)H1 * KP * 2;
    unsigned short* maskbuf = (unsigned short*)p;
    unsigned long long* mask64 = (unsigned long long*)p;

    const int npack = (B * 52 + 255) / 256;        // 1664
    const int nw1t  = (H1 * KP + 255) / 256;       // 650
    prep_fused<<<npack + nw1t, 256, 0, stream>>>(state, action, W1, A_sw, B_sw, B, npack);
    gemm_mask<<<dim3(B / 64, 5), 256, 0, stream>>>(A_sw, B_sw, b1, maskbuf);
    snn_actor<<<B / 4, 256, 0, stream>>>(mask64, state, action,
                                         W1, b1, W2, b2, W3, b3, out);
}